// Round 13
// baseline (2113.372 us; speedup 1.0000x reference)
//
#include <hip/hip_runtime.h>
#include <hip/hip_bf16.h>

#define EMB_D 100
#define HID 64
#define G4 256
#define BATCH 128
#define SEQ 1024
#define TOK 16

typedef _Float16 half2v __attribute__((ext_vector_type(2)));
typedef unsigned short u16;
typedef unsigned int   u32;

__device__ __forceinline__ float sigf(float x) { return 1.0f / (1.0f + __expf(-x)); }
__device__ __forceinline__ float tanh_fast(float x) {
  float t = __expf(-2.0f * fabsf(x));
  float r = (1.0f - t) / (1.0f + t);
  return copysignf(r, x);
}

__device__ __forceinline__ float dot2(u32 h, u32 w, float acc) {
  return __builtin_amdgcn_fdot2(__builtin_bit_cast(half2v, h),
                                __builtin_bit_cast(half2v, w), acc, false);
}

__device__ __forceinline__ u32 packh2(float lo, float hi) {
  u16 a = __builtin_bit_cast(u16, (_Float16)lo);
  u16 b = __builtin_bit_cast(u16, (_Float16)hi);
  return (u32)a | ((u32)b << 16);
}

#define QP_XOR1 0xB1
#define QP_XOR2 0x4E
#define QP_XOR3 0x1B
#define QPERM(x, ctrl)                                                        \
  __builtin_bit_cast(float, __builtin_amdgcn_mov_dpp(                         \
      __builtin_bit_cast(int, (x)), (ctrl), 0xF, 0xF, true))

// --- prep: combined biases, transposed Wih0, f16-packed recurrent weights ---
__global__ void prep_kernel(const float* __restrict__ Wih0,
                            const float* __restrict__ Whh0, const float* __restrict__ Wih1,
                            const float* __restrict__ Whh1,
                            const float* __restrict__ bih0, const float* __restrict__ bhh0,
                            const float* __restrict__ bih1, const float* __restrict__ bhh1,
                            float* __restrict__ Wih0T, float* __restrict__ b0c,
                            float* __restrict__ b1c,
                            u32* __restrict__ Whh0h, u32* __restrict__ Wih1h,
                            u32* __restrict__ Whh1h) {
  int g = threadIdx.x;
  b0c[g] = bih0[g] + bhh0[g];
  b1c[g] = bih1[g] + bhh1[g];
  for (int d = 0; d < EMB_D; ++d) Wih0T[d * G4 + g] = Wih0[g * EMB_D + d];
  for (int d = 0; d < HID / 2; ++d) {
    Whh0h[g * 32 + d] = packh2(Whh0[g * HID + 2 * d], Whh0[g * HID + 2 * d + 1]);
    Wih1h[g * 32 + d] = packh2(Wih1[g * HID + 2 * d], Wih1[g * HID + 2 * d + 1]);
    Whh1h[g * 32 + d] = packh2(Whh1[g * HID + 2 * d], Whh1[g * HID + 2 * d + 1]);
  }
}

// --- xw0 (unchanged from R8) ---
__global__ __attribute__((amdgpu_waves_per_eu(1, 4))) __launch_bounds__(256)
void xw0_kernel(
    const int* __restrict__ x, const float* __restrict__ emb,
    const float* __restrict__ Wih0T, const float* __restrict__ b0c,
    _Float16* __restrict__ xw0h) {
  __shared__ int sidx[TOK];
  __shared__ float erow[TOK][EMB_D];
  int g = threadIdx.x;
  long t0 = (long)blockIdx.x * TOK;

  if (g < TOK) sidx[g] = x[t0 + g];
  __syncthreads();
  for (int i = g; i < TOK * EMB_D; i += 256) {
    int tok = i / EMB_D;
    int d = i - tok * EMB_D;
    erow[tok][d] = emb[(long)sidx[tok] * EMB_D + d];
  }

  float w[EMB_D];
  #pragma unroll
  for (int d = 0; d < EMB_D; ++d) w[d] = Wih0T[d * G4 + g];
  float bb = b0c[g];
  __syncthreads();

  for (int tok = 0; tok < TOK; ++tok) {
    const float* ev = erow[tok];
    float a0 = bb, a1 = 0.f, a2 = 0.f, a3 = 0.f;
    #pragma unroll
    for (int d = 0; d < EMB_D; d += 4) {
      a0 = fmaf(w[d],     ev[d],     a0);
      a1 = fmaf(w[d + 1], ev[d + 1], a1);
      a2 = fmaf(w[d + 2], ev[d + 2], a2);
      a3 = fmaf(w[d + 3], ev[d + 3], a3);
    }
    xw0h[(t0 + tok) * G4 + g] = (_Float16)((a0 + a1) + (a2 + a3));
  }
}

// --- fused recurrence (R8 verbatim: best known, 815 us, absmax 0.0) ---
__global__ __launch_bounds__(512, 2) void lstm_fused_kernel(
    const _Float16* __restrict__ xw0h,
    const u32* __restrict__ Whh0h, const u32* __restrict__ Wih1h,
    const u32* __restrict__ Whh1h, const float* __restrict__ b1c,
    const float* __restrict__ W1, const float* __restrict__ clsb1,
    const float* __restrict__ W2, const float* __restrict__ clsb2,
    float* __restrict__ out) {
  int tid = threadIdx.x;
  int lane = tid & 63;
  int w = tid >> 6;
  bool isL1 = (w >= 4);
  int eg = isL1 ? (w - 4) : w;
  int e = eg * 16 + (lane >> 2);
  int k = lane & 3;
  int row = k * HID + e;
  int b = blockIdx.x;

  __shared__ alignas(16) _Float16 h0s[2][HID];
  __shared__ alignas(16) _Float16 h1s[2][HID];
  __shared__ alignas(16) float hf[HID];

  uint4 wA[8], wB[8];
  if (!isL1) {
    const uint4* p = (const uint4*)(Whh0h + row * 32);
    #pragma unroll
    for (int c = 0; c < 8; ++c) wA[c] = p[c];
  } else {
    const uint4* p = (const uint4*)(Wih1h + row * 32);
    const uint4* q = (const uint4*)(Whh1h + row * 32);
    #pragma unroll
    for (int c = 0; c < 8; ++c) { wA[c] = p[c]; wB[c] = q[c]; }
  }
  float bias = isL1 ? b1c[row] : 0.f;

  if (tid < 2 * HID) {
    int j = tid & (HID - 1);
    if (tid < HID) { h0s[0][j] = (_Float16)0.f; h0s[1][j] = (_Float16)0.f; }
    else           { h1s[0][j] = (_Float16)0.f; h1s[1][j] = (_Float16)0.f; }
  }

  const _Float16* xr = xw0h + (long)b * SEQ * G4 + row;
  float xw_t = 0.f, xw_t1 = 0.f;
  if (!isL1) { xw_t = (float)xr[0]; xw_t1 = (float)xr[G4]; }
  float c_reg = 0.f;
  __syncthreads();

  for (int t = 0; t < SEQ; ++t) {
    float xw_t2 = 0.f;
    if (!isL1) {
      int tn = (t + 2 < SEQ) ? (t + 2) : (SEQ - 1);
      xw_t2 = (float)xr[(long)tn * G4];
    }
    int rb = (t + 1) & 1, wbuf = t & 1;
    const uint4* h0p = (const uint4*)h0s[rb];
    float a0, a1 = 0.f, a2 = 0.f, a3 = 0.f;
    if (!isL1) {
      a0 = xw_t;
      #pragma unroll
      for (int c = 0; c < 8; ++c) {
        uint4 h = h0p[c];
        a0 = dot2(h.x, wA[c].x, a0);
        a1 = dot2(h.y, wA[c].y, a1);
        a2 = dot2(h.z, wA[c].z, a2);
        a3 = dot2(h.w, wA[c].w, a3);
      }
    } else {
      const uint4* h1p = (const uint4*)h1s[rb];
      a0 = bias;
      #pragma unroll
      for (int c = 0; c < 8; ++c) {
        uint4 h = h0p[c];
        a0 = dot2(h.x, wA[c].x, a0);
        a1 = dot2(h.y, wA[c].y, a1);
        a2 = dot2(h.z, wA[c].z, a2);
        a3 = dot2(h.w, wA[c].w, a3);
      }
      #pragma unroll
      for (int c = 0; c < 8; ++c) {
        uint4 h = h1p[c];
        a0 = dot2(h.x, wB[c].x, a0);
        a1 = dot2(h.y, wB[c].y, a1);
        a2 = dot2(h.z, wB[c].z, a2);
        a3 = dot2(h.w, wB[c].w, a3);
      }
    }
    float gown = (a0 + a1) + (a2 + a3);
    float gx1 = QPERM(gown, QP_XOR1);
    float gx2 = QPERM(gown, QP_XOR2);
    float gx3 = QPERM(gown, QP_XOR3);
    bool act = (!isL1) || (t > 0);
    if (act) {
      c_reg = sigf(gx1) * c_reg + sigf(gown) * tanh_fast(gx2);
      float hv = sigf(gx3) * tanh_fast(c_reg);
      if (k == 0) {
        _Float16 h16 = (_Float16)hv;
        if (isL1) h1s[wbuf][e] = h16; else h0s[wbuf][e] = h16;
      }
    }
    xw_t = xw_t1; xw_t1 = xw_t2;
    asm volatile("s_waitcnt lgkmcnt(0)" ::: "memory");
    __builtin_amdgcn_s_barrier();
    asm volatile("" ::: "memory");
  }

  if (isL1) {
    const uint4* h0p = (const uint4*)h0s[1];
    const uint4* h1p = (const uint4*)h1s[1];
    float a0 = bias, a1 = 0.f, a2 = 0.f, a3 = 0.f;
    #pragma unroll
    for (int c = 0; c < 8; ++c) {
      uint4 h = h0p[c];
      a0 = dot2(h.x, wA[c].x, a0);
      a1 = dot2(h.y, wA[c].y, a1);
      a2 = dot2(h.z, wA[c].z, a2);
      a3 = dot2(h.w, wA[c].w, a3);
    }
    #pragma unroll
    for (int c = 0; c < 8; ++c) {
      uint4 h = h1p[c];
      a0 = dot2(h.x, wB[c].x, a0);
      a1 = dot2(h.y, wB[c].y, a1);
      a2 = dot2(h.z, wB[c].z, a2);
      a3 = dot2(h.w, wB[c].w, a3);
    }
    float gown = (a0 + a1) + (a2 + a3);
    float gx1 = QPERM(gown, QP_XOR1);
    float gx2 = QPERM(gown, QP_XOR2);
    float gx3 = QPERM(gown, QP_XOR3);
    c_reg = sigf(gx1) * c_reg + sigf(gown) * tanh_fast(gx2);
    float hv = sigf(gx3) * tanh_fast(c_reg);
    if (k == 0) hf[e] = hv;
  }
  __syncthreads();

  if (w == 0) {
    int j = lane;
    const float4* wp = (const float4*)(W1 + j * HID);
    const float4* hp = (const float4*)hf;
    float z0 = clsb1[j], z1 = 0.f, z2 = 0.f, z3 = 0.f;
    #pragma unroll
    for (int c = 0; c < 16; ++c) {
      float4 wv = wp[c];
      float4 hv = hp[c];
      z0 = fmaf(hv.x, wv.x, z0);
      z1 = fmaf(hv.y, wv.y, z1);
      z2 = fmaf(hv.z, wv.z, z2);
      z3 = fmaf(hv.w, wv.w, z3);
    }
    float z = fmaxf((z0 + z1) + (z2 + z3), 0.f);
    float v = z * W2[j];
    v += __shfl_xor(v, 1);
    v += __shfl_xor(v, 2);
    v += __shfl_xor(v, 4);
    v += __shfl_xor(v, 8);
    v += __shfl_xor(v, 16);
    v += __shfl_xor(v, 32);
    if (lane == 0) out[b] = sigf(v + clsb2[0]);
  }
}

// ================= ABLATION A: sync/LDS skeleton, 2048 iters =================
// R8's per-step skeleton minus dots/act: uniform ds_read_b128 (8 per L0 wave,
// 16 per L1 wave), fold, conditional ds_write_b16, lgkmcnt(0), s_barrier.
// 2048 iters (2x SEQ) so it is the slowest dispatch -> visible in top-5.
__global__ __launch_bounds__(512, 2) void abl_sync_kernel(float* __restrict__ sink) {
  int tid = threadIdx.x;
  int l = tid & 63;
  int w = tid >> 6;
  bool isL1 = (w >= 4);
  int eg = isL1 ? (w - 4) : w;
  int e = eg * 16 + (l >> 2);
  int k = l & 3;
  __shared__ alignas(16) _Float16 h0s[2][HID];
  __shared__ alignas(16) _Float16 h1s[2][HID];
  if (tid < 2 * HID) {
    int j = tid & (HID - 1);
    if (tid < HID) { h0s[0][j] = (_Float16)0.f; h0s[1][j] = (_Float16)0.f; }
    else           { h1s[0][j] = (_Float16)0.f; h1s[1][j] = (_Float16)0.f; }
  }
  __syncthreads();
  float acc = 0.f;
  for (int t = 0; t < 2 * SEQ; ++t) {
    int rb = (t + 1) & 1, wb = t & 1;
    const uint4* h0p = (const uint4*)h0s[rb];
    u32 s = 0;
    #pragma unroll
    for (int c = 0; c < 8; ++c) { uint4 h = h0p[c]; s += h.x + h.w; }
    if (isL1) {
      const uint4* h1p = (const uint4*)h1s[rb];
      #pragma unroll
      for (int c = 0; c < 8; ++c) { uint4 h = h1p[c]; s += h.y + h.z; }
    }
    acc = acc * 0.5f + (float)(s & 0xFFu);
    if (k == 0) {
      _Float16 h16 = (_Float16)acc;
      if (isL1) h1s[wb][e] = h16; else h0s[wb][e] = h16;
    }
    asm volatile("s_waitcnt lgkmcnt(0)" ::: "memory");
    __builtin_amdgcn_s_barrier();
  }
  if (tid == 0) sink[blockIdx.x] = acc;
}

// ================= ABLATION B: compute skeleton, 1024 iters =================
// R8's L1 per-step compute (64 dot2 + 3 DPP + activation chain) on register
// data with cross-iteration feedback; NO LDS, NO barrier.
__global__ __attribute__((amdgpu_waves_per_eu(1, 2))) __launch_bounds__(512)
void abl_comp_kernel(const u32* __restrict__ Wih1h, const u32* __restrict__ Whh1h,
                     float* __restrict__ sink) {
  int tid = threadIdx.x;
  int row = tid & 255;
  uint4 wA[8], wB[8];
  const uint4* p = (const uint4*)(Wih1h + row * 32);
  const uint4* q = (const uint4*)(Whh1h + row * 32);
  #pragma unroll
  for (int c = 0; c < 8; ++c) { wA[c] = p[c]; wB[c] = q[c]; }
  #pragma unroll
  for (int c = 0; c < 8; ++c)
    asm volatile("" : "+v"(wA[c].x), "+v"(wA[c].y), "+v"(wA[c].z), "+v"(wA[c].w),
                      "+v"(wB[c].x), "+v"(wB[c].y), "+v"(wB[c].z), "+v"(wB[c].w));
  uint4 hc[8];
  #pragma unroll
  for (int c = 0; c < 8; ++c) hc[c] = wB[c];
  float c_reg = 0.f;
  for (int t = 0; t < SEQ; ++t) {
    float a0 = 0.f, a1 = 0.f, a2 = 0.f, a3 = 0.f;
    #pragma unroll
    for (int c = 0; c < 8; ++c) {
      a0 = dot2(hc[c].x, wA[c].x, a0);
      a1 = dot2(hc[c].y, wA[c].y, a1);
      a2 = dot2(hc[c].z, wA[c].z, a2);
      a3 = dot2(hc[c].w, wA[c].w, a3);
    }
    #pragma unroll
    for (int c = 0; c < 8; ++c) {
      a0 = dot2(hc[c].x, wB[c].x, a0);
      a1 = dot2(hc[c].y, wB[c].y, a1);
      a2 = dot2(hc[c].z, wB[c].z, a2);
      a3 = dot2(hc[c].w, wB[c].w, a3);
    }
    float gown = (a0 + a1) + (a2 + a3);
    float gx1 = QPERM(gown, QP_XOR1);
    float gx2 = QPERM(gown, QP_XOR2);
    float gx3 = QPERM(gown, QP_XOR3);
    c_reg = sigf(gx1) * c_reg + sigf(gown) * tanh_fast(gx2);
    float hv = sigf(gx3) * tanh_fast(c_reg);
    hc[0].x ^= (__builtin_bit_cast(u32, hv) & 0xFFFFu);   // serialize iterations
  }
  if (tid == 0) sink[256 + blockIdx.x] = c_reg + (float)(hc[0].x & 1u);
}

extern "C" void kernel_launch(void* const* d_in, const int* in_sizes, int n_in,
                              void* d_out, int out_size, void* d_ws, size_t ws_size,
                              hipStream_t stream) {
  const int*   x    = (const int*)d_in[0];
  const float* emb  = (const float*)d_in[1];
  const float* Wih0 = (const float*)d_in[2];
  const float* Whh0 = (const float*)d_in[3];
  const float* bih0 = (const float*)d_in[4];
  const float* bhh0 = (const float*)d_in[5];
  const float* Wih1 = (const float*)d_in[6];
  const float* Whh1 = (const float*)d_in[7];
  const float* bih1 = (const float*)d_in[8];
  const float* bhh1 = (const float*)d_in[9];
  const float* W1   = (const float*)d_in[10];
  const float* b1   = (const float*)d_in[11];
  const float* W2   = (const float*)d_in[12];
  const float* b2   = (const float*)d_in[13];
  float* out = (float*)d_out;

  char* ws = (char*)d_ws;
  char* ws0 = ws;
  const size_t XW0_BYTES = (size_t)BATCH * SEQ * G4 * sizeof(_Float16);  // 67108864
  _Float16* xw0h = (_Float16*)ws;                 ws += XW0_BYTES;
  float* Wih0T   = (float*)ws;                    ws += (size_t)EMB_D * G4 * sizeof(float);
  float* b0c     = (float*)ws;                    ws += G4 * sizeof(float);
  float* b1c     = (float*)ws;                    ws += G4 * sizeof(float);
  u32* Whh0h     = (u32*)ws;                      ws += (size_t)G4 * 32 * sizeof(u32);
  u32* Wih1h     = (u32*)ws;                      ws += (size_t)G4 * 32 * sizeof(u32);
  u32* Whh1h     = (u32*)ws;                      ws += (size_t)G4 * 32 * sizeof(u32);

  prep_kernel<<<1, 256, 0, stream>>>(Wih0, Whh0, Wih1, Whh1, bih0, bhh0, bih1, bhh1,
                                     Wih0T, b0c, b1c, Whh0h, Wih1h, Whh1h);
  xw0_kernel<<<(BATCH * SEQ) / TOK, 256, 0, stream>>>(x, emb, Wih0T, b0c, xw0h);
  lstm_fused_kernel<<<BATCH, 512, 0, stream>>>(xw0h, Whh0h, Wih1h, Whh1h, b1c,
                                               W1, b1, W2, b2, out);

  // ---- diagnostic ablations (write only to far d_ws region) ----
  const size_t SINK_OFF = (size_t)120 * 1024 * 1024;
  if (ws_size >= SINK_OFF + 4096) {
    float* sink = (float*)(ws0 + SINK_OFF);
    abl_sync_kernel<<<BATCH, 512, 0, stream>>>(sink);
    abl_comp_kernel<<<BATCH, 512, 0, stream>>>(Wih1h, Whh1h, sink);
  }
}

// Round 14
// 881.974 us; speedup vs baseline: 2.3962x; 2.3962x over previous
//
#include <hip/hip_runtime.h>
#include <hip/hip_bf16.h>

#define EMB_D 100
#define HID 64
#define G4 256
#define BATCH 128
#define SEQ 1024
#define TOK 16

typedef _Float16 half2v __attribute__((ext_vector_type(2)));
typedef unsigned short u16;
typedef unsigned int   u32;

// fast reciprocal: single v_rcp_f32 (~1e-6 rel err) instead of IEEE div
// sequence (v_div_scale+v_rcp+v_div_fmas+v_div_fixup, ~9 serial instrs).
__device__ __forceinline__ float rcpf(float x) { return __builtin_amdgcn_rcpf(x); }
__device__ __forceinline__ float sigf(float x) {
  return rcpf(1.0f + __expf(-x));
}
__device__ __forceinline__ float tanh_fast(float x) {
  float t = __expf(-2.0f * fabsf(x));
  float r = (1.0f - t) * rcpf(1.0f + t);
  return copysignf(r, x);
}

__device__ __forceinline__ float dot2(u32 h, u32 w, float acc) {
  return __builtin_amdgcn_fdot2(__builtin_bit_cast(half2v, h),
                                __builtin_bit_cast(half2v, w), acc, false);
}

__device__ __forceinline__ u32 packh2(float lo, float hi) {
  u16 a = __builtin_bit_cast(u16, (_Float16)lo);
  u16 b = __builtin_bit_cast(u16, (_Float16)hi);
  return (u32)a | ((u32)b << 16);
}

#define QP_XOR1 0xB1
#define QP_XOR2 0x4E
#define QP_XOR3 0x1B
#define QPERM(x, ctrl)                                                        \
  __builtin_bit_cast(float, __builtin_amdgcn_mov_dpp(                         \
      __builtin_bit_cast(int, (x)), (ctrl), 0xF, 0xF, true))

// --- prep: combined biases, transposed Wih0, f16-packed recurrent weights ---
__global__ void prep_kernel(const float* __restrict__ Wih0,
                            const float* __restrict__ Whh0, const float* __restrict__ Wih1,
                            const float* __restrict__ Whh1,
                            const float* __restrict__ bih0, const float* __restrict__ bhh0,
                            const float* __restrict__ bih1, const float* __restrict__ bhh1,
                            float* __restrict__ Wih0T, float* __restrict__ b0c,
                            float* __restrict__ b1c,
                            u32* __restrict__ Whh0h, u32* __restrict__ Wih1h,
                            u32* __restrict__ Whh1h) {
  int g = threadIdx.x;
  b0c[g] = bih0[g] + bhh0[g];
  b1c[g] = bih1[g] + bhh1[g];
  for (int d = 0; d < EMB_D; ++d) Wih0T[d * G4 + g] = Wih0[g * EMB_D + d];
  for (int d = 0; d < HID / 2; ++d) {
    Whh0h[g * 32 + d] = packh2(Whh0[g * HID + 2 * d], Whh0[g * HID + 2 * d + 1]);
    Wih1h[g * 32 + d] = packh2(Wih1[g * HID + 2 * d], Wih1[g * HID + 2 * d + 1]);
    Whh1h[g * 32 + d] = packh2(Whh1[g * HID + 2 * d], Whh1[g * HID + 2 * d + 1]);
  }
}

// --- xw0[token][gate] = emb[x[token]] . Wih0[gate] + b0, stored f16 ---
__global__ __attribute__((amdgpu_waves_per_eu(1, 4))) __launch_bounds__(256)
void xw0_kernel(
    const int* __restrict__ x, const float* __restrict__ emb,
    const float* __restrict__ Wih0T, const float* __restrict__ b0c,
    _Float16* __restrict__ xw0h) {
  __shared__ int sidx[TOK];
  __shared__ float erow[TOK][EMB_D];
  int g = threadIdx.x;
  long t0 = (long)blockIdx.x * TOK;

  if (g < TOK) sidx[g] = x[t0 + g];
  __syncthreads();
  for (int i = g; i < TOK * 25; i += 256) {
    int tok = i / 25;
    int d4 = i - tok * 25;
    const float4 v = *(const float4*)(emb + (size_t)sidx[tok] * EMB_D + 4 * d4);
    erow[tok][4 * d4]     = v.x;
    erow[tok][4 * d4 + 1] = v.y;
    erow[tok][4 * d4 + 2] = v.z;
    erow[tok][4 * d4 + 3] = v.w;
  }

  float w[EMB_D];
  #pragma unroll
  for (int d = 0; d < EMB_D; ++d) w[d] = Wih0T[d * G4 + g];
  float bb = b0c[g];
  __syncthreads();

  for (int tok = 0; tok < TOK; ++tok) {
    const float* ev = erow[tok];
    float a0 = bb, a1 = 0.f, a2 = 0.f, a3 = 0.f;
    #pragma unroll
    for (int d = 0; d < EMB_D; d += 4) {
      a0 = fmaf(w[d],     ev[d],     a0);
      a1 = fmaf(w[d + 1], ev[d + 1], a1);
      a2 = fmaf(w[d + 2], ev[d + 2], a2);
      a3 = fmaf(w[d + 3], ev[d + 3], a3);
    }
    xw0h[(t0 + tok) * G4 + g] = (_Float16)((a0 + a1) + (a2 + a3));
  }
}

// --- fused recurrence (R8 structure + rcp-based act + split L1 chains) ---
__global__ __launch_bounds__(512, 2) void lstm_fused_kernel(
    const _Float16* __restrict__ xw0h,
    const u32* __restrict__ Whh0h, const u32* __restrict__ Wih1h,
    const u32* __restrict__ Whh1h, const float* __restrict__ b1c,
    const float* __restrict__ W1, const float* __restrict__ clsb1,
    const float* __restrict__ W2, const float* __restrict__ clsb2,
    float* __restrict__ out) {
  int tid = threadIdx.x;
  int lane = tid & 63;
  int w = tid >> 6;
  bool isL1 = (w >= 4);
  int eg = isL1 ? (w - 4) : w;
  int e = eg * 16 + (lane >> 2);
  int k = lane & 3;
  int row = k * HID + e;
  int b = blockIdx.x;

  __shared__ alignas(16) _Float16 h0s[2][HID];
  __shared__ alignas(16) _Float16 h1s[2][HID];
  __shared__ alignas(16) float hf[HID];

  uint4 wA[8], wB[8];
  if (!isL1) {
    const uint4* p = (const uint4*)(Whh0h + row * 32);
    #pragma unroll
    for (int c = 0; c < 8; ++c) wA[c] = p[c];
  } else {
    const uint4* p = (const uint4*)(Wih1h + row * 32);
    const uint4* q = (const uint4*)(Whh1h + row * 32);
    #pragma unroll
    for (int c = 0; c < 8; ++c) { wA[c] = p[c]; wB[c] = q[c]; }
  }
  float bias = isL1 ? b1c[row] : 0.f;

  if (tid < 2 * HID) {
    int j = tid & (HID - 1);
    if (tid < HID) { h0s[0][j] = (_Float16)0.f; h0s[1][j] = (_Float16)0.f; }
    else           { h1s[0][j] = (_Float16)0.f; h1s[1][j] = (_Float16)0.f; }
  }

  const _Float16* xr = xw0h + (long)b * SEQ * G4 + row;
  float xw_t = 0.f, xw_t1 = 0.f;
  if (!isL1) { xw_t = (float)xr[0]; xw_t1 = (float)xr[G4]; }
  float c_reg = 0.f;
  __syncthreads();

  for (int t = 0; t < SEQ; ++t) {
    float xw_t2 = 0.f;
    if (!isL1) {
      int tn = (t + 2 < SEQ) ? (t + 2) : (SEQ - 1);
      xw_t2 = (float)xr[(long)tn * G4];
    }
    int rb = (t + 1) & 1, wbuf = t & 1;
    const uint4* h0p = (const uint4*)h0s[rb];
    float gown;
    if (!isL1) {
      float a0 = xw_t, a1 = 0.f, a2 = 0.f, a3 = 0.f;
      #pragma unroll
      for (int c = 0; c < 8; ++c) {
        uint4 h = h0p[c];
        a0 = dot2(h.x, wA[c].x, a0);
        a1 = dot2(h.y, wA[c].y, a1);
        a2 = dot2(h.z, wA[c].z, a2);
        a3 = dot2(h.w, wA[c].w, a3);
      }
      gown = (a0 + a1) + (a2 + a3);
    } else {
      const uint4* h1p = (const uint4*)h1s[rb];
      float a0 = bias, a1 = 0.f, a2 = 0.f, a3 = 0.f;
      float b0 = 0.f, b1 = 0.f, b2 = 0.f, b3 = 0.f;   // separate chains (8-deep)
      #pragma unroll
      for (int c = 0; c < 8; ++c) {
        uint4 h = h0p[c];
        uint4 g2 = h1p[c];
        a0 = dot2(h.x, wA[c].x, a0);
        a1 = dot2(h.y, wA[c].y, a1);
        a2 = dot2(h.z, wA[c].z, a2);
        a3 = dot2(h.w, wA[c].w, a3);
        b0 = dot2(g2.x, wB[c].x, b0);
        b1 = dot2(g2.y, wB[c].y, b1);
        b2 = dot2(g2.z, wB[c].z, b2);
        b3 = dot2(g2.w, wB[c].w, b3);
      }
      gown = ((a0 + a1) + (a2 + a3)) + ((b0 + b1) + (b2 + b3));
    }
    float gx1 = QPERM(gown, QP_XOR1);
    float gx2 = QPERM(gown, QP_XOR2);
    float gx3 = QPERM(gown, QP_XOR3);
    bool act = (!isL1) || (t > 0);
    if (act) {
      c_reg = sigf(gx1) * c_reg + sigf(gown) * tanh_fast(gx2);
      float hv = sigf(gx3) * tanh_fast(c_reg);
      if (k == 0) {
        _Float16 h16 = (_Float16)hv;
        if (isL1) h1s[wbuf][e] = h16; else h0s[wbuf][e] = h16;
      }
    }
    xw_t = xw_t1; xw_t1 = xw_t2;
    asm volatile("s_waitcnt lgkmcnt(0)" ::: "memory");
    __builtin_amdgcn_s_barrier();
    asm volatile("" ::: "memory");
  }

  if (isL1) {
    const uint4* h0p = (const uint4*)h0s[1];
    const uint4* h1p = (const uint4*)h1s[1];
    float a0 = bias, a1 = 0.f, a2 = 0.f, a3 = 0.f;
    float b0 = 0.f, b1 = 0.f, b2 = 0.f, b3 = 0.f;
    #pragma unroll
    for (int c = 0; c < 8; ++c) {
      uint4 h = h0p[c];
      uint4 g2 = h1p[c];
      a0 = dot2(h.x, wA[c].x, a0);
      a1 = dot2(h.y, wA[c].y, a1);
      a2 = dot2(h.z, wA[c].z, a2);
      a3 = dot2(h.w, wA[c].w, a3);
      b0 = dot2(g2.x, wB[c].x, b0);
      b1 = dot2(g2.y, wB[c].y, b1);
      b2 = dot2(g2.z, wB[c].z, b2);
      b3 = dot2(g2.w, wB[c].w, b3);
    }
    float gown = ((a0 + a1) + (a2 + a3)) + ((b0 + b1) + (b2 + b3));
    float gx1 = QPERM(gown, QP_XOR1);
    float gx2 = QPERM(gown, QP_XOR2);
    float gx3 = QPERM(gown, QP_XOR3);
    c_reg = sigf(gx1) * c_reg + sigf(gown) * tanh_fast(gx2);
    float hv = sigf(gx3) * tanh_fast(c_reg);
    if (k == 0) hf[e] = hv;
  }
  __syncthreads();

  if (w == 0) {
    int j = lane;
    const float4* wp = (const float4*)(W1 + j * HID);
    const float4* hp = (const float4*)hf;
    float z0 = clsb1[j], z1 = 0.f, z2 = 0.f, z3 = 0.f;
    #pragma unroll
    for (int c = 0; c < 16; ++c) {
      float4 wv = wp[c];
      float4 hv = hp[c];
      z0 = fmaf(hv.x, wv.x, z0);
      z1 = fmaf(hv.y, wv.y, z1);
      z2 = fmaf(hv.z, wv.z, z2);
      z3 = fmaf(hv.w, wv.w, z3);
    }
    float z = fmaxf((z0 + z1) + (z2 + z3), 0.f);
    float v = z * W2[j];
    v += __shfl_xor(v, 1);
    v += __shfl_xor(v, 2);
    v += __shfl_xor(v, 4);
    v += __shfl_xor(v, 8);
    v += __shfl_xor(v, 16);
    v += __shfl_xor(v, 32);
    if (lane == 0) out[b] = sigf(v + clsb2[0]);
  }
}

extern "C" void kernel_launch(void* const* d_in, const int* in_sizes, int n_in,
                              void* d_out, int out_size, void* d_ws, size_t ws_size,
                              hipStream_t stream) {
  const int*   x    = (const int*)d_in[0];
  const float* emb  = (const float*)d_in[1];
  const float* Wih0 = (const float*)d_in[2];
  const float* Whh0 = (const float*)d_in[3];
  const float* bih0 = (const float*)d_in[4];
  const float* bhh0 = (const float*)d_in[5];
  const float* Wih1 = (const float*)d_in[6];
  const float* Whh1 = (const float*)d_in[7];
  const float* bih1 = (const float*)d_in[8];
  const float* bhh1 = (const float*)d_in[9];
  const float* W1   = (const float*)d_in[10];
  const float* b1   = (const float*)d_in[11];
  const float* W2   = (const float*)d_in[12];
  const float* b2   = (const float*)d_in[13];
  float* out = (float*)d_out;

  char* ws = (char*)d_ws;
  const size_t XW0_BYTES = (size_t)BATCH * SEQ * G4 * sizeof(_Float16);  // 67108864
  _Float16* xw0h = (_Float16*)ws;                 ws += XW0_BYTES;
  float* Wih0T   = (float*)ws;                    ws += (size_t)EMB_D * G4 * sizeof(float);
  float* b0c     = (float*)ws;                    ws += G4 * sizeof(float);
  float* b1c     = (float*)ws;                    ws += G4 * sizeof(float);
  u32* Whh0h     = (u32*)ws;                      ws += (size_t)G4 * 32 * sizeof(u32);
  u32* Wih1h     = (u32*)ws;                      ws += (size_t)G4 * 32 * sizeof(u32);
  u32* Whh1h     = (u32*)ws;                      ws += (size_t)G4 * 32 * sizeof(u32);

  prep_kernel<<<1, 256, 0, stream>>>(Wih0, Whh0, Wih1, Whh1, bih0, bhh0, bih1, bhh1,
                                     Wih0T, b0c, b1c, Whh0h, Wih1h, Whh1h);
  xw0_kernel<<<(BATCH * SEQ) / TOK, 256, 0, stream>>>(x, emb, Wih0T, b0c, xw0h);
  lstm_fused_kernel<<<BATCH, 512, 0, stream>>>(xw0h, Whh0h, Wih1h, Whh1h, b1c,
                                               W1, b1, W2, b2, out);
}

// Round 15
// 782.772 us; speedup vs baseline: 2.6999x; 1.1267x over previous
//
#include <hip/hip_runtime.h>
#include <hip/hip_bf16.h>

#define EMB_D 100
#define HID 64
#define G4 256
#define BATCH 128
#define SEQ 1024
#define TOK 64

typedef _Float16 half2v __attribute__((ext_vector_type(2)));
typedef unsigned short u16;
typedef unsigned int   u32;

__device__ __forceinline__ float rcpf(float x) { return __builtin_amdgcn_rcpf(x); }
__device__ __forceinline__ float sigf(float x) { return rcpf(1.0f + __expf(-x)); }
__device__ __forceinline__ float tanh_fast(float x) {
  float t = __expf(-2.0f * fabsf(x));
  float r = (1.0f - t) * rcpf(1.0f + t);
  return copysignf(r, x);
}
__device__ __forceinline__ float dot2(u32 h, u32 w, float acc) {
  return __builtin_amdgcn_fdot2(__builtin_bit_cast(half2v, h),
                                __builtin_bit_cast(half2v, w), acc, false);
}
__device__ __forceinline__ u32 packh2(float lo, float hi) {
  u16 a = __builtin_bit_cast(u16, (_Float16)lo);
  u16 b = __builtin_bit_cast(u16, (_Float16)hi);
  return (u32)a | ((u32)b << 16);
}
#define QP_XOR1 0xB1
#define QP_XOR2 0x4E
#define QP_XOR3 0x1B
#define QPERM(x, ctrl)                                                        \
  __builtin_bit_cast(float, __builtin_amdgcn_mov_dpp(                         \
      __builtin_bit_cast(int, (x)), (ctrl), 0xF, 0xF, true))

// --- prep: biases, f16-pair-packed Wih0 (transposed), packed recurrent W ---
__global__ void prep_kernel(const float* __restrict__ Wih0,
                            const float* __restrict__ Whh0, const float* __restrict__ Wih1,
                            const float* __restrict__ Whh1,
                            const float* __restrict__ bih0, const float* __restrict__ bhh0,
                            const float* __restrict__ bih1, const float* __restrict__ bhh1,
                            u32* __restrict__ Wih0T2, float* __restrict__ b0c,
                            float* __restrict__ b1c,
                            u32* __restrict__ Whh0h, u32* __restrict__ Wih1h,
                            u32* __restrict__ Whh1h) {
  int g = threadIdx.x;
  b0c[g] = bih0[g] + bhh0[g];
  b1c[g] = bih1[g] + bhh1[g];
  for (int dp = 0; dp < 50; ++dp)
    Wih0T2[dp * G4 + g] = packh2(Wih0[g * EMB_D + 2 * dp], Wih0[g * EMB_D + 2 * dp + 1]);
  for (int d = 0; d < 32; ++d) {
    Whh0h[g * 32 + d] = packh2(Whh0[g * HID + 2 * d], Whh0[g * HID + 2 * d + 1]);
    Wih1h[g * 32 + d] = packh2(Wih1[g * HID + 2 * d], Wih1[g * HID + 2 * d + 1]);
    Whh1h[g * 32 + d] = packh2(Whh1[g * HID + 2 * d], Whh1[g * HID + 2 * d + 1]);
  }
}

// --- xw0: f16 dot2 GEMV, 64 tokens/block (R11 version, ~100us faster) ---
__global__ __attribute__((amdgpu_waves_per_eu(1, 4))) __launch_bounds__(256)
void xw0_kernel(
    const int* __restrict__ x, const float* __restrict__ emb,
    const u32* __restrict__ Wih0T2, const float* __restrict__ b0c,
    _Float16* __restrict__ xw0h) {
  __shared__ int sidx[TOK];
  __shared__ alignas(16) u32 erow[TOK][52];
  int g = threadIdx.x;
  long t0 = (long)blockIdx.x * TOK;

  if (g < TOK) sidx[g] = x[t0 + g];
  __syncthreads();
  for (int i = g; i < TOK * 50; i += 256) {
    int tok = i / 50, dp = i - tok * 50;
    const float* er = emb + (size_t)sidx[tok] * EMB_D + 2 * dp;
    erow[tok][dp] = packh2(er[0], er[1]);
  }
  for (int i = g; i < TOK * 2; i += 256) erow[i >> 1][50 + (i & 1)] = 0;

  u32 wreg[52];
  #pragma unroll
  for (int dp = 0; dp < 50; ++dp) wreg[dp] = Wih0T2[dp * G4 + g];
  wreg[50] = 0; wreg[51] = 0;
  float bb = b0c[g];
  __syncthreads();

  for (int tok = 0; tok < TOK; ++tok) {
    const uint4* ep = (const uint4*)erow[tok];
    float a0 = bb, a1 = 0.f, a2 = 0.f, a3 = 0.f;
    #pragma unroll
    for (int c = 0; c < 13; ++c) {
      uint4 hv = ep[c];
      a0 = dot2(hv.x, wreg[4 * c],     a0);
      a1 = dot2(hv.y, wreg[4 * c + 1], a1);
      a2 = dot2(hv.z, wreg[4 * c + 2], a2);
      a3 = dot2(hv.w, wreg[4 * c + 3], a3);
    }
    xw0h[(t0 + tok) * G4 + g] = (_Float16)((a0 + a1) + (a2 + a3));
  }
}

// --- fused recurrence: balanced 48/48 wave split, one barrier/step ---
// 128 blocks x 512 threads (8 waves). Lane: e = eg*16+(lane>>2), k = lane&3,
// row = k*64+e (quartet per lane -> lane-local activation via 3 QPERMs).
// Waves 0-3 (L0): Whh0[row]@h0_{t-1} (32 dot2) + Wih1[row]@h0_{t-1} K-lo
//   (16 dot2) -> ps[t&1]; act -> h0_t. Waves 4-7 (L1): Wih1[row] K-hi @
//   h0_{t-2} (16 dot2) + Whh1[row]@h1_{t-3} (32 dot2) + ps[(t+1)&1] + bias;
//   act -> h1_{t-2}. h0 triple-buffered (L1 reads lag-2), h1 parity-buffered.
__global__ __launch_bounds__(512, 2) void lstm_fused_kernel(
    const _Float16* __restrict__ xw0h,
    const u32* __restrict__ Whh0h, const u32* __restrict__ Wih1h,
    const u32* __restrict__ Whh1h, const float* __restrict__ b1c,
    const float* __restrict__ W1, const float* __restrict__ clsb1,
    const float* __restrict__ W2, const float* __restrict__ clsb2,
    float* __restrict__ out) {
  int tid = threadIdx.x;
  int lane = tid & 63;
  int w = tid >> 6;
  bool isL1 = (w >= 4);
  int eg = isL1 ? (w - 4) : w;
  int e = eg * 16 + (lane >> 2);
  int k = lane & 3;
  int row = k * HID + e;
  int b = blockIdx.x;

  __shared__ alignas(16) _Float16 h0s[3][HID];
  __shared__ alignas(16) _Float16 h1s[2][HID];
  __shared__ float ps[2][4][65];            // [buf][k][e], conflict-free
  __shared__ alignas(16) float hf[HID];

  // weights: L0 lane: Whh0 row (8 uint4) + Wih1 row K-lo (4). L1 lane:
  // Wih1 row K-hi (4) + Whh1 row (8). 12 uint4 = 48 VGPR either way.
  uint4 wA[8], wP[4];
  if (!isL1) {
    const uint4* p = (const uint4*)(Whh0h + row * 32);
    #pragma unroll
    for (int c = 0; c < 8; ++c) wA[c] = p[c];
    const uint4* q = (const uint4*)(Wih1h + row * 32);
    #pragma unroll
    for (int c = 0; c < 4; ++c) wP[c] = q[c];
  } else {
    const uint4* q = (const uint4*)(Wih1h + row * 32);
    #pragma unroll
    for (int c = 0; c < 4; ++c) wP[c] = q[4 + c];      // K-hi
    const uint4* p = (const uint4*)(Whh1h + row * 32);
    #pragma unroll
    for (int c = 0; c < 8; ++c) wA[c] = p[c];          // Whh1
  }
  float bias = isL1 ? b1c[row] : 0.f;

  if (tid < 3 * HID) ((u16*)h0s)[tid] = 0;
  if (tid < 2 * HID) ((u16*)h1s)[tid] = 0;

  const _Float16* xr = xw0h + (long)b * SEQ * G4 + row;
  float xw_t = 0.f, xw_t1 = 0.f;
  if (!isL1) { xw_t = (float)xr[0]; xw_t1 = (float)xr[G4]; }
  float c_reg = 0.f;
  __syncthreads();

  int h0w = 0, h0rA = 2, h0rB = 1;   // t%3, (t+2)%3, (t+1)%3
  for (int t = 0; t <= SEQ + 1; ++t) {
    if (!isL1) {
      if (t <= SEQ) {
        const uint4* h0p = (const uint4*)h0s[h0rA];
        uint4 hc[8];
        #pragma unroll
        for (int c = 0; c < 8; ++c) hc[c] = h0p[c];
        // Wih1 K-lo partial for L1 (uses chunks 0-3)
        {
          float p0 = 0.f, p1 = 0.f, p2 = 0.f, p3 = 0.f;
          #pragma unroll
          for (int c = 0; c < 4; ++c) {
            p0 = dot2(hc[c].x, wP[c].x, p0);
            p1 = dot2(hc[c].y, wP[c].y, p1);
            p2 = dot2(hc[c].z, wP[c].z, p2);
            p3 = dot2(hc[c].w, wP[c].w, p3);
          }
          ps[t & 1][k][e] = (p0 + p1) + (p2 + p3);
        }
        if (t < SEQ) {
          float a0 = xw_t, a1 = 0.f, a2 = 0.f, a3 = 0.f;
          #pragma unroll
          for (int c = 0; c < 8; ++c) {
            a0 = dot2(hc[c].x, wA[c].x, a0);
            a1 = dot2(hc[c].y, wA[c].y, a1);
            a2 = dot2(hc[c].z, wA[c].z, a2);
            a3 = dot2(hc[c].w, wA[c].w, a3);
          }
          float gown = (a0 + a1) + (a2 + a3);
          float gx1 = QPERM(gown, QP_XOR1);
          float gx2 = QPERM(gown, QP_XOR2);
          float gx3 = QPERM(gown, QP_XOR3);
          c_reg = sigf(gx1) * c_reg + sigf(gown) * tanh_fast(gx2);
          float hv = sigf(gx3) * tanh_fast(c_reg);
          if (k == 0) h0s[h0w][e] = (_Float16)hv;
          float xw_t2 = 0.f;
          int tn = (t + 2 < SEQ) ? (t + 2) : (SEQ - 1);
          xw_t2 = (float)xr[(long)tn * G4];
          xw_t = xw_t1; xw_t1 = xw_t2;
        }
      }
    } else {
      if (t >= 2) {
        const uint4* h0p = (const uint4*)h0s[h0rB];   // h0_{t-2}
        const uint4* h1p = (const uint4*)h1s[(t + 1) & 1];
        float a0 = bias, a1 = 0.f, a2 = 0.f, a3 = 0.f;
        float b0 = 0.f, b1 = 0.f, b2 = 0.f, b3 = 0.f;
        #pragma unroll
        for (int c = 0; c < 4; ++c) {                 // Wih1 K-hi: chunks 4-7
          uint4 h = h0p[4 + c];
          a0 = dot2(h.x, wP[c].x, a0);
          a1 = dot2(h.y, wP[c].y, a1);
          a2 = dot2(h.z, wP[c].z, a2);
          a3 = dot2(h.w, wP[c].w, a3);
        }
        #pragma unroll
        for (int c = 0; c < 8; ++c) {                 // Whh1 @ h1_{t-3}
          uint4 h = h1p[c];
          b0 = dot2(h.x, wA[c].x, b0);
          b1 = dot2(h.y, wA[c].y, b1);
          b2 = dot2(h.z, wA[c].z, b2);
          b3 = dot2(h.w, wA[c].w, b3);
        }
        float gown = ((a0 + a1) + (a2 + a3)) + ((b0 + b1) + (b2 + b3))
                     + ps[(t + 1) & 1][k][e];
        float gx1 = QPERM(gown, QP_XOR1);
        float gx2 = QPERM(gown, QP_XOR2);
        float gx3 = QPERM(gown, QP_XOR3);
        c_reg = sigf(gx1) * c_reg + sigf(gown) * tanh_fast(gx2);
        float hv = sigf(gx3) * tanh_fast(c_reg);
        if (k == 0) {
          h1s[t & 1][e] = (_Float16)hv;
          if (t == SEQ + 1) hf[e] = hv;
        }
      }
    }
    // rotate h0 buffer indices: +1 mod 3
    h0w = (h0w == 2) ? 0 : h0w + 1;
    h0rA = (h0rA == 2) ? 0 : h0rA + 1;
    h0rB = (h0rB == 2) ? 0 : h0rB + 1;
    asm volatile("s_waitcnt lgkmcnt(0)" ::: "memory");
    __builtin_amdgcn_s_barrier();
    asm volatile("" ::: "memory");
  }

  // classifier (wave 0): z = relu(h1.W1^T + b1); out = sigmoid(z.W2 + b2)
  if (w == 0) {
    int j = lane;
    const float4* wp = (const float4*)(W1 + j * HID);
    const float4* hp = (const float4*)hf;
    float z0 = clsb1[j], z1 = 0.f, z2 = 0.f, z3 = 0.f;
    #pragma unroll
    for (int c = 0; c < 16; ++c) {
      float4 wv = wp[c];
      float4 hv = hp[c];
      z0 = fmaf(hv.x, wv.x, z0);
      z1 = fmaf(hv.y, wv.y, z1);
      z2 = fmaf(hv.z, wv.z, z2);
      z3 = fmaf(hv.w, wv.w, z3);
    }
    float z = fmaxf((z0 + z1) + (z2 + z3), 0.f);
    float v = z * W2[j];
    v += __shfl_xor(v, 1);
    v += __shfl_xor(v, 2);
    v += __shfl_xor(v, 4);
    v += __shfl_xor(v, 8);
    v += __shfl_xor(v, 16);
    v += __shfl_xor(v, 32);
    if (lane == 0) out[b] = sigf(v + clsb2[0]);
  }
}

extern "C" void kernel_launch(void* const* d_in, const int* in_sizes, int n_in,
                              void* d_out, int out_size, void* d_ws, size_t ws_size,
                              hipStream_t stream) {
  const int*   x    = (const int*)d_in[0];
  const float* emb  = (const float*)d_in[1];
  const float* Wih0 = (const float*)d_in[2];
  const float* Whh0 = (const float*)d_in[3];
  const float* bih0 = (const float*)d_in[4];
  const float* bhh0 = (const float*)d_in[5];
  const float* Wih1 = (const float*)d_in[6];
  const float* Whh1 = (const float*)d_in[7];
  const float* bih1 = (const float*)d_in[8];
  const float* bhh1 = (const float*)d_in[9];
  const float* W1   = (const float*)d_in[10];
  const float* b1   = (const float*)d_in[11];
  const float* W2   = (const float*)d_in[12];
  const float* b2   = (const float*)d_in[13];
  float* out = (float*)d_out;

  char* ws = (char*)d_ws;
  const size_t XW0_BYTES = (size_t)BATCH * SEQ * G4 * sizeof(_Float16);  // 67108864
  _Float16* xw0h = (_Float16*)ws;     ws += XW0_BYTES;
  u32* Wih0T2    = (u32*)ws;          ws += (size_t)50 * G4 * sizeof(u32);
  float* b0c     = (float*)ws;        ws += G4 * sizeof(float);
  float* b1c     = (float*)ws;        ws += G4 * sizeof(float);
  u32* Whh0h     = (u32*)ws;          ws += (size_t)G4 * 32 * sizeof(u32);
  u32* Wih1h     = (u32*)ws;          ws += (size_t)G4 * 32 * sizeof(u32);
  u32* Whh1h     = (u32*)ws;          ws += (size_t)G4 * 32 * sizeof(u32);

  prep_kernel<<<1, 256, 0, stream>>>(Wih0, Whh0, Wih1, Whh1, bih0, bhh0, bih1, bhh1,
                                     Wih0T2, b0c, b1c, Whh0h, Wih1h, Whh1h);
  xw0_kernel<<<(BATCH * SEQ) / TOK, 256, 0, stream>>>(x, emb, Wih0T2, b0c, xw0h);
  lstm_fused_kernel<<<BATCH, 512, 0, stream>>>(xw0h, Whh0h, Wih1h, Whh1h, b1c,
                                               W1, b1, W2, b2, out);
}

// Round 16
// 737.568 us; speedup vs baseline: 2.8653x; 1.0613x over previous
//
#include <hip/hip_runtime.h>
#include <hip/hip_bf16.h>

#define EMB_D 100
#define HID 64
#define G4 256
#define BATCH 128
#define SEQ 1024
#define TOK 64
#define LOG2E 1.44269504f

typedef _Float16 half2v __attribute__((ext_vector_type(2)));
typedef unsigned short u16;
typedef unsigned int   u32;

__device__ __forceinline__ float rcpf(float x) { return __builtin_amdgcn_rcpf(x); }
__device__ __forceinline__ float ex2(float x) { return __builtin_amdgcn_exp2f(x); }
// pre-scaled inputs (x' = log2e * x): sigmoid/tanh without the exp pre-multiply
__device__ __forceinline__ float sig_pre(float xp) { return rcpf(1.0f + ex2(-xp)); }
__device__ __forceinline__ float tanh_pre(float xp) {
  float t = ex2(-2.0f * fabsf(xp));
  return copysignf((1.0f - t) * rcpf(1.0f + t), xp);
}
__device__ __forceinline__ float tanh_nat(float x) {   // natural-scale input (c state)
  float t = ex2(-2.885390082f * fabsf(x));
  return copysignf((1.0f - t) * rcpf(1.0f + t), x);
}
__device__ __forceinline__ float sig_nat(float x) { return rcpf(1.0f + ex2(-LOG2E * x)); }

__device__ __forceinline__ float dot2(u32 h, u32 w, float acc) {
  return __builtin_amdgcn_fdot2(__builtin_bit_cast(half2v, h),
                                __builtin_bit_cast(half2v, w), acc, false);
}
__device__ __forceinline__ u32 packh2(float lo, float hi) {
  u16 a = __builtin_bit_cast(u16, (_Float16)lo);
  u16 b = __builtin_bit_cast(u16, (_Float16)hi);
  return (u32)a | ((u32)b << 16);
}
#define QP_XOR1 0xB1
#define QP_XOR2 0x4E
#define QP_XOR3 0x1B
#define QPERM(x, ctrl)                                                        \
  __builtin_bit_cast(float, __builtin_amdgcn_mov_dpp(                         \
      __builtin_bit_cast(int, (x)), (ctrl), 0xF, 0xF, true))

// --- prep: biases + packed weights, ALL pre-scaled by log2(e) ---
__global__ void prep_kernel(const float* __restrict__ Wih0,
                            const float* __restrict__ Whh0, const float* __restrict__ Wih1,
                            const float* __restrict__ Whh1,
                            const float* __restrict__ bih0, const float* __restrict__ bhh0,
                            const float* __restrict__ bih1, const float* __restrict__ bhh1,
                            u32* __restrict__ Wih0T2, float* __restrict__ b0c,
                            float* __restrict__ b1c,
                            u32* __restrict__ Whh0h, u32* __restrict__ Wih1h,
                            u32* __restrict__ Whh1h) {
  int g = threadIdx.x;
  b0c[g] = (bih0[g] + bhh0[g]) * LOG2E;
  b1c[g] = (bih1[g] + bhh1[g]) * LOG2E;
  for (int dp = 0; dp < 50; ++dp)
    Wih0T2[dp * G4 + g] = packh2(Wih0[g * EMB_D + 2 * dp] * LOG2E,
                                 Wih0[g * EMB_D + 2 * dp + 1] * LOG2E);
  for (int d = 0; d < 32; ++d) {
    Whh0h[g * 32 + d] = packh2(Whh0[g * HID + 2 * d] * LOG2E, Whh0[g * HID + 2 * d + 1] * LOG2E);
    Wih1h[g * 32 + d] = packh2(Wih1[g * HID + 2 * d] * LOG2E, Wih1[g * HID + 2 * d + 1] * LOG2E);
    Whh1h[g * 32 + d] = packh2(Whh1[g * HID + 2 * d] * LOG2E, Whh1[g * HID + 2 * d + 1] * LOG2E);
  }
}

// --- xw0: f16 dot2 GEMV, 64 tokens/block; output pre-scaled via weights ---
__global__ __attribute__((amdgpu_waves_per_eu(1, 4))) __launch_bounds__(256)
void xw0_kernel(
    const int* __restrict__ x, const float* __restrict__ emb,
    const u32* __restrict__ Wih0T2, const float* __restrict__ b0c,
    _Float16* __restrict__ xw0h) {
  __shared__ int sidx[TOK];
  __shared__ alignas(16) u32 erow[TOK][52];
  int g = threadIdx.x;
  long t0 = (long)blockIdx.x * TOK;

  if (g < TOK) sidx[g] = x[t0 + g];
  __syncthreads();
  for (int i = g; i < TOK * 50; i += 256) {
    int tok = i / 50, dp = i - tok * 50;
    const float* er = emb + (size_t)sidx[tok] * EMB_D + 2 * dp;
    erow[tok][dp] = packh2(er[0], er[1]);
  }
  for (int i = g; i < TOK * 2; i += 256) erow[i >> 1][50 + (i & 1)] = 0;

  u32 wreg[52];
  #pragma unroll
  for (int dp = 0; dp < 50; ++dp) wreg[dp] = Wih0T2[dp * G4 + g];
  wreg[50] = 0; wreg[51] = 0;
  float bb = b0c[g];
  __syncthreads();

  for (int tok = 0; tok < TOK; ++tok) {
    const uint4* ep = (const uint4*)erow[tok];
    float a0 = bb, a1 = 0.f, a2 = 0.f, a3 = 0.f;
    #pragma unroll
    for (int c = 0; c < 13; ++c) {
      uint4 hv = ep[c];
      a0 = dot2(hv.x, wreg[4 * c],     a0);
      a1 = dot2(hv.y, wreg[4 * c + 1], a1);
      a2 = dot2(hv.z, wreg[4 * c + 2], a2);
      a3 = dot2(hv.w, wreg[4 * c + 3], a3);
    }
    xw0h[(t0 + tok) * G4 + g] = (_Float16)((a0 + a1) + (a2 + a3));
  }
}

// --- fused recurrence: BOTH layers per lane, 4 waves, 1 barrier/step ---
// 128 blocks x 256 threads (1 block/CU, 1 wave/SIMD). Lane (e = w*16+(l>>2),
// k = l&3) owns gate-row k*64+e of Whh0, Wih1, Whh1 (24 uint4 = 96 VGPR,
// pinned). Step t: one shared h0_{t-1} read feeds Whh0 (-> h0_t) AND Wih1
// (-> h1_{t-1} with Whh1@h1_{t-2}); two act chains run as ILP in-lane; (i,f,
// g,o) gathered by 3 DPP quad_perms; k==0 writes h0 & h1. No ps round-trip.
__global__ __attribute__((amdgpu_waves_per_eu(1, 1))) __launch_bounds__(256)
void lstm_fused_kernel(
    const _Float16* __restrict__ xw0h,
    const u32* __restrict__ Whh0h, const u32* __restrict__ Wih1h,
    const u32* __restrict__ Whh1h, const float* __restrict__ b1c,
    const float* __restrict__ W1, const float* __restrict__ clsb1,
    const float* __restrict__ W2, const float* __restrict__ clsb2,
    float* __restrict__ out) {
  int tid = threadIdx.x;
  int l = tid & 63;
  int w = tid >> 6;
  int e = w * 16 + (l >> 2);
  int k = l & 3;
  int row = k * HID + e;
  int b = blockIdx.x;

  __shared__ alignas(16) _Float16 h0s[2][HID];
  __shared__ alignas(16) _Float16 h1s[2][HID];
  __shared__ alignas(16) float hf[HID];

  uint4 w0[8], w1[8], w2[8];
  {
    const uint4* p0 = (const uint4*)(Whh0h + row * 32);
    const uint4* p1 = (const uint4*)(Wih1h + row * 32);
    const uint4* p2 = (const uint4*)(Whh1h + row * 32);
    #pragma unroll
    for (int c = 0; c < 8; ++c) { w0[c] = p0[c]; w1[c] = p1[c]; w2[c] = p2[c]; }
  }
  #pragma unroll
  for (int c = 0; c < 8; ++c) {
    asm volatile("" : "+v"(w0[c].x), "+v"(w0[c].y), "+v"(w0[c].z), "+v"(w0[c].w));
    asm volatile("" : "+v"(w1[c].x), "+v"(w1[c].y), "+v"(w1[c].z), "+v"(w1[c].w));
    asm volatile("" : "+v"(w2[c].x), "+v"(w2[c].y), "+v"(w2[c].z), "+v"(w2[c].w));
  }
  float bias = b1c[row];

  if (tid < 128) ((u16*)h0s)[tid] = 0;
  else           ((u16*)h1s)[tid - 128] = 0;

  const _Float16* xr = xw0h + (long)b * SEQ * G4 + row;
  float xw_t = (float)xr[0];
  float xw_t1 = (float)xr[G4];
  float c0 = 0.f, c1 = 0.f;
  __syncthreads();

  for (int t = 0; t <= SEQ; ++t) {
    int rb = (t + 1) & 1, wb = t & 1;
    uint4 hc0[8], hc1[8];
    {
      const uint4* p0 = (const uint4*)h0s[rb];
      const uint4* p1 = (const uint4*)h1s[rb];
      #pragma unroll
      for (int c = 0; c < 8; ++c) { hc0[c] = p0[c]; hc1[c] = p1[c]; }
    }
    int tn = (t + 2 < SEQ) ? (t + 2) : (SEQ - 1);
    float xw_t2 = (float)xr[(long)tn * G4];

    // L0: h0_t  (skip at t==SEQ)
    if (t < SEQ) {
      float a0 = xw_t, a1 = 0.f, a2 = 0.f, a3 = 0.f;
      #pragma unroll
      for (int c = 0; c < 8; ++c) {
        a0 = dot2(hc0[c].x, w0[c].x, a0);
        a1 = dot2(hc0[c].y, w0[c].y, a1);
        a2 = dot2(hc0[c].z, w0[c].z, a2);
        a3 = dot2(hc0[c].w, w0[c].w, a3);
      }
      float g0 = (a0 + a1) + (a2 + a3);
      float g0x1 = QPERM(g0, QP_XOR1);
      float g0x2 = QPERM(g0, QP_XOR2);
      float g0x3 = QPERM(g0, QP_XOR3);
      c0 = sig_pre(g0x1) * c0 + sig_pre(g0) * tanh_pre(g0x2);
      float hv0 = sig_pre(g0x3) * tanh_nat(c0);
      if (k == 0) h0s[wb][e] = (_Float16)hv0;
    }

    // L1: h1_{t-1} from h0_{t-1} and h1_{t-2}  (active t>=1)
    if (t >= 1) {
      float a0 = bias, a1 = 0.f, a2 = 0.f, a3 = 0.f;
      float b0 = 0.f, b1 = 0.f, b2 = 0.f, b3 = 0.f;
      #pragma unroll
      for (int c = 0; c < 8; ++c) {
        a0 = dot2(hc0[c].x, w1[c].x, a0);
        a1 = dot2(hc0[c].y, w1[c].y, a1);
        a2 = dot2(hc0[c].z, w1[c].z, a2);
        a3 = dot2(hc0[c].w, w1[c].w, a3);
        b0 = dot2(hc1[c].x, w2[c].x, b0);
        b1 = dot2(hc1[c].y, w2[c].y, b1);
        b2 = dot2(hc1[c].z, w2[c].z, b2);
        b3 = dot2(hc1[c].w, w2[c].w, b3);
      }
      float g1 = ((a0 + a1) + (a2 + a3)) + ((b0 + b1) + (b2 + b3));
      float g1x1 = QPERM(g1, QP_XOR1);
      float g1x2 = QPERM(g1, QP_XOR2);
      float g1x3 = QPERM(g1, QP_XOR3);
      c1 = sig_pre(g1x1) * c1 + sig_pre(g1) * tanh_pre(g1x2);
      float hv1 = sig_pre(g1x3) * tanh_nat(c1);
      if (k == 0) {
        h1s[wb][e] = (_Float16)hv1;
        if (t == SEQ) hf[e] = hv1;
      }
    }

    xw_t = xw_t1; xw_t1 = xw_t2;
    asm volatile("s_waitcnt lgkmcnt(0)" ::: "memory");
    __builtin_amdgcn_s_barrier();
    asm volatile("" ::: "memory");
  }
  __syncthreads();

  // classifier (wave 0): z = relu(h1.W1^T + b1); out = sigmoid(z.W2 + b2)
  if (w == 0) {
    int j = l;
    const float4* wp = (const float4*)(W1 + j * HID);
    const float4* hp = (const float4*)hf;
    float z0 = clsb1[j], z1 = 0.f, z2 = 0.f, z3 = 0.f;
    #pragma unroll
    for (int c = 0; c < 16; ++c) {
      float4 wv = wp[c];
      float4 hv = hp[c];
      z0 = fmaf(hv.x, wv.x, z0);
      z1 = fmaf(hv.y, wv.y, z1);
      z2 = fmaf(hv.z, wv.z, z2);
      z3 = fmaf(hv.w, wv.w, z3);
    }
    float z = fmaxf((z0 + z1) + (z2 + z3), 0.f);
    float v = z * W2[j];
    v += __shfl_xor(v, 1);
    v += __shfl_xor(v, 2);
    v += __shfl_xor(v, 4);
    v += __shfl_xor(v, 8);
    v += __shfl_xor(v, 16);
    v += __shfl_xor(v, 32);
    if (l == 0) out[b] = sig_nat(v + clsb2[0]);
  }
}

extern "C" void kernel_launch(void* const* d_in, const int* in_sizes, int n_in,
                              void* d_out, int out_size, void* d_ws, size_t ws_size,
                              hipStream_t stream) {
  const int*   x    = (const int*)d_in[0];
  const float* emb  = (const float*)d_in[1];
  const float* Wih0 = (const float*)d_in[2];
  const float* Whh0 = (const float*)d_in[3];
  const float* bih0 = (const float*)d_in[4];
  const float* bhh0 = (const float*)d_in[5];
  const float* Wih1 = (const float*)d_in[6];
  const float* Whh1 = (const float*)d_in[7];
  const float* bih1 = (const float*)d_in[8];
  const float* bhh1 = (const float*)d_in[9];
  const float* W1   = (const float*)d_in[10];
  const float* b1   = (const float*)d_in[11];
  const float* W2   = (const float*)d_in[12];
  const float* b2   = (const float*)d_in[13];
  float* out = (float*)d_out;

  char* ws = (char*)d_ws;
  const size_t XW0_BYTES = (size_t)BATCH * SEQ * G4 * sizeof(_Float16);  // 67108864
  _Float16* xw0h = (_Float16*)ws;     ws += XW0_BYTES;
  u32* Wih0T2    = (u32*)ws;          ws += (size_t)50 * G4 * sizeof(u32);
  float* b0c     = (float*)ws;        ws += G4 * sizeof(float);
  float* b1c     = (float*)ws;        ws += G4 * sizeof(float);
  u32* Whh0h     = (u32*)ws;          ws += (size_t)G4 * 32 * sizeof(u32);
  u32* Wih1h     = (u32*)ws;          ws += (size_t)G4 * 32 * sizeof(u32);
  u32* Whh1h     = (u32*)ws;          ws += (size_t)G4 * 32 * sizeof(u32);

  prep_kernel<<<1, 256, 0, stream>>>(Wih0, Whh0, Wih1, Whh1, bih0, bhh0, bih1, bhh1,
                                     Wih0T2, b0c, b1c, Whh0h, Wih1h, Whh1h);
  xw0_kernel<<<(BATCH * SEQ) / TOK, 256, 0, stream>>>(x, emb, Wih0T2, b0c, xw0h);
  lstm_fused_kernel<<<BATCH, 256, 0, stream>>>(xw0h, Whh0h, Wih1h, Whh1h, b1c,
                                               W1, b1, W2, b2, out);
}